// Round 1
// baseline (2480.471 us; speedup 1.0000x reference)
//
#include <hip/hip_runtime.h>

// GCN forward: enc -> pre -> 3x{transform, scatter-add w/ sym norm, bias, LN+ReLU} -> head
// N=50000 nodes, E=1.6M edges, D=128, DIN=100, DOUT=40.

#define NNODES 50000
#define NEDGES 1600000
#define DMID 128
#define DINN 100
#define DOUTN 40

// ---------------- degree / norm ----------------
__global__ void fill_deg(float* __restrict__ deg) {
    int n = blockIdx.x * 256 + threadIdx.x;
    if (n < NNODES) deg[n] = 1.0f;  // self-loop
}

__global__ void accum_deg(const int* __restrict__ dst, float* __restrict__ deg) {
    int e = blockIdx.x * 256 + threadIdx.x;
    if (e < NEDGES) atomicAdd(&deg[dst[e]], 1.0f);
}

__global__ void finish_dinv(float* __restrict__ deg) {
    int n = blockIdx.x * 256 + threadIdx.x;
    if (n < NNODES) deg[n] = rsqrtf(deg[n]);  // deg >= 1 always
}

// ---------------- row-block GEMM: C[M,128] = A[M,K] @ B[K,128] (+bias) ----------------
template <int K>
__global__ __launch_bounds__(256) void gemm128(const float* __restrict__ A,
                                               const float* __restrict__ B,
                                               const float* __restrict__ bias,
                                               float* __restrict__ C, int M) {
    __shared__ float as[16][K];
    int tid = threadIdx.x;
    int row0 = blockIdx.x * 16;
    for (int idx = tid; idx < 16 * K; idx += 256) {
        int r = idx / K, k = idx - r * K;
        int row = row0 + r;
        as[r][k] = (row < M) ? A[(size_t)row * K + k] : 0.0f;
    }
    __syncthreads();
    int d = tid & 127;       // output column
    int rg = tid >> 7;       // 0..1, row group
    float acc[8];
#pragma unroll
    for (int r = 0; r < 8; r++) acc[r] = 0.0f;
#pragma unroll 4
    for (int k = 0; k < K; k++) {
        float wv = B[k * 128 + d];
#pragma unroll
        for (int r = 0; r < 8; r++) acc[r] += as[rg * 8 + r][k] * wv;
    }
    float bv = bias ? bias[d] : 0.0f;
#pragma unroll
    for (int r = 0; r < 8; r++) {
        int row = row0 + rg * 8 + r;
        if (row < M) C[(size_t)row * 128 + d] = acc[r] + bv;
    }
}

// ---------------- init rows with bias ----------------
__global__ void init_rows(float* __restrict__ buf, const float* __restrict__ bias) {
    int t = blockIdx.x * 256 + threadIdx.x;
    if (t < NNODES * DMID) buf[t] = bias[t & 127];
}

// ---------------- scatter-add: out[dst] += hw[src] * dinv[src]*dinv[dst] ----------------
__global__ void scatter_edges(const float* __restrict__ hw, const int* __restrict__ srcs,
                              const int* __restrict__ dsts, const float* __restrict__ dinv,
                              float* __restrict__ out) {
    int t = blockIdx.x * 256 + threadIdx.x;
    int edge = t >> 7;
    int d = t & 127;
    const int total = NEDGES + NNODES;
    if (edge >= total) return;
    int s, dt;
    if (edge < NEDGES) {
        s = srcs[edge];
        dt = dsts[edge];
    } else {
        s = dt = edge - NEDGES;  // self-loop
    }
    float nrm = dinv[s] * dinv[dt];
    float v = hw[(size_t)s * 128 + d] * nrm;
    atomicAdd(&out[(size_t)dt * 128 + d], v);
}

// ---------------- LayerNorm + ReLU (one wave per row) ----------------
__global__ void ln_relu(float* __restrict__ h, const float* __restrict__ g,
                        const float* __restrict__ b, int M) {
    int row = blockIdx.x * 4 + (threadIdx.x >> 6);
    int lane = threadIdx.x & 63;
    if (row >= M) return;
    float2 v = *(const float2*)&h[(size_t)row * 128 + lane * 2];
    float sum = v.x + v.y;
#pragma unroll
    for (int off = 32; off >= 1; off >>= 1) sum += __shfl_xor(sum, off);
    float mu = sum * (1.0f / 128.0f);
    float dx = v.x - mu, dy = v.y - mu;
    float vs = dx * dx + dy * dy;
#pragma unroll
    for (int off = 32; off >= 1; off >>= 1) vs += __shfl_xor(vs, off);
    float rstd = rsqrtf(vs * (1.0f / 128.0f) + 1e-5f);
    float2 gg = *(const float2*)&g[lane * 2];
    float2 bb = *(const float2*)&b[lane * 2];
    float ox = fmaxf(dx * rstd * gg.x + bb.x, 0.0f);
    float oy = fmaxf(dy * rstd * gg.y + bb.y, 0.0f);
    *(float2*)&h[(size_t)row * 128 + lane * 2] = make_float2(ox, oy);
}

// ---------------- head: out[M,40] = h[M,128] @ W[128,40] + bias ----------------
__global__ __launch_bounds__(256) void head_gemm(const float* __restrict__ h,
                                                 const float* __restrict__ W,
                                                 const float* __restrict__ bias,
                                                 float* __restrict__ out, int M) {
    __shared__ float hs[32][128];
    int tid = threadIdx.x;
    int row0 = blockIdx.x * 32;
    for (int idx = tid; idx < 32 * 128; idx += 256) {
        int r = idx >> 7, k = idx & 127;
        int row = row0 + r;
        hs[r][k] = (row < M) ? h[(size_t)row * 128 + k] : 0.0f;
    }
    __syncthreads();
    int d = tid & 63;
    int rg = tid >> 6;  // 0..3 -> 8 rows each
    if (d < DOUTN) {
        float acc[8];
#pragma unroll
        for (int r = 0; r < 8; r++) acc[r] = 0.0f;
#pragma unroll 4
        for (int k = 0; k < 128; k++) {
            float wv = W[k * DOUTN + d];
#pragma unroll
            for (int r = 0; r < 8; r++) acc[r] += hs[rg * 8 + r][k] * wv;
        }
        float bv = bias[d];
#pragma unroll
        for (int r = 0; r < 8; r++) {
            int row = row0 + rg * 8 + r;
            if (row < M) out[(size_t)row * DOUTN + d] = acc[r] + bv;
        }
    }
}

extern "C" void kernel_launch(void* const* d_in, const int* in_sizes, int n_in,
                              void* d_out, int out_size, void* d_ws, size_t ws_size,
                              hipStream_t stream) {
    const float* x = (const float*)d_in[0];
    const int* ei = (const int*)d_in[1];
    const int* esrc = ei;
    const int* edst = ei + NEDGES;
    const float* W_enc = (const float*)d_in[2];
    const float* b_enc = (const float*)d_in[3];
    const float* W_pre = (const float*)d_in[4];
    const float* b_pre = (const float*)d_in[5];
    const float* Wc = (const float*)d_in[6];
    const float* bc = (const float*)d_in[7];
    const float* ln_g = (const float*)d_in[8];
    const float* ln_b = (const float*)d_in[9];
    const float* W_head = (const float*)d_in[10];
    const float* b_head = (const float*)d_in[11];
    float* out = (float*)d_out;

    char* ws = (char*)d_ws;
    const size_t nodeBytes = (size_t)NNODES * DMID * sizeof(float);  // 25.6 MB
    float* bufA = (float*)ws;
    float* bufB = (float*)(ws + nodeBytes);
    float* dinv = (float*)(ws + 2 * nodeBytes);

    // degrees -> dinv
    fill_deg<<<(NNODES + 255) / 256, 256, 0, stream>>>(dinv);
    accum_deg<<<(NEDGES + 255) / 256, 256, 0, stream>>>(edst, dinv);
    finish_dinv<<<(NNODES + 255) / 256, 256, 0, stream>>>(dinv);

    // encoder + pre_mp
    gemm128<DINN><<<(NNODES + 15) / 16, 256, 0, stream>>>(x, W_enc, b_enc, bufA, NNODES);
    gemm128<128><<<(NNODES + 15) / 16, 256, 0, stream>>>(bufA, W_pre, b_pre, bufB, NNODES);

    // 3 GCN layers; h lives in bufB
    const long long totalT = (long long)(NEDGES + NNODES) * 128;
    for (int l = 0; l < 3; l++) {
        gemm128<128><<<(NNODES + 15) / 16, 256, 0, stream>>>(bufB, Wc + (size_t)l * 128 * 128,
                                                             nullptr, bufA, NNODES);  // hw
        init_rows<<<(NNODES * DMID + 255) / 256, 256, 0, stream>>>(bufB, bc + (size_t)l * 128);
        scatter_edges<<<(int)((totalT + 255) / 256), 256, 0, stream>>>(bufA, esrc, edst, dinv,
                                                                       bufB);
        if (l < 2)
            ln_relu<<<(NNODES + 3) / 4, 256, 0, stream>>>(bufB, ln_g + (size_t)l * 128,
                                                          ln_b + (size_t)l * 128, NNODES);
    }

    // head
    head_gemm<<<(NNODES + 31) / 32, 256, 0, stream>>>(bufB, W_head, b_head, out, NNODES);
}

// Round 2
// 735.442 us; speedup vs baseline: 3.3728x; 3.3728x over previous
//
#include <hip/hip_runtime.h>

// GCN forward: enc -> pre -> 3x{transform, CSR pull-aggregate + bias + LN + ReLU} -> head
// N=50000 nodes, E=1.6M edges, D=128, DIN=100, DOUT=40.
// Aggregation is pull-based over an on-device CSR (sorted by dst) -- no fp32 atomics.

#define NNODES 50000
#define NEDGES 1600000
#define DMID 128
#define DINN 100
#define DOUTN 40
#define NB1 ((NNODES + 255) / 256)  // 196 blocks for scan

// ---------------- CSR build ----------------
__global__ void zero_counts(int* __restrict__ counts) {
    int n = blockIdx.x * 256 + threadIdx.x;
    if (n < NNODES) counts[n] = 0;
}

__global__ void hist_dst(const int* __restrict__ dst, int* __restrict__ counts) {
    int e = blockIdx.x * 256 + threadIdx.x;
    if (e < NEDGES) atomicAdd(&counts[dst[e]], 1);
}

__global__ void dinv_from_counts(const int* __restrict__ counts, float* __restrict__ dinv) {
    int n = blockIdx.x * 256 + threadIdx.x;
    if (n < NNODES) dinv[n] = rsqrtf((float)(counts[n] + 1));  // +1 self loop
}

// hierarchical exclusive scan of counts -> row_ptr
__global__ __launch_bounds__(256) void scan1(const int* __restrict__ counts,
                                             int* __restrict__ row_ptr, int* __restrict__ bsum) {
    int tid = threadIdx.x;
    int i = blockIdx.x * 256 + tid;
    int v = (i < NNODES) ? counts[i] : 0;
    int lane = tid & 63, w = tid >> 6;
    int x = v;
#pragma unroll
    for (int off = 1; off < 64; off <<= 1) {
        int t = __shfl_up(x, off);
        if (lane >= off) x += t;
    }
    __shared__ int wsum[4];
    if (lane == 63) wsum[w] = x;
    __syncthreads();
    if (tid == 0) {
        int s = 0;
#pragma unroll
        for (int k = 0; k < 4; k++) { int t = wsum[k]; wsum[k] = s; s += t; }
        bsum[blockIdx.x] = s;
    }
    __syncthreads();
    int incl = x + wsum[w];
    if (i < NNODES) row_ptr[i] = incl - v;  // block-local exclusive
}

__global__ __launch_bounds__(256) void scan2(const int* __restrict__ bsum,
                                             int* __restrict__ boff, int* __restrict__ row_ptr) {
    int tid = threadIdx.x;
    int v = (tid < NB1) ? bsum[tid] : 0;
    int lane = tid & 63, w = tid >> 6;
    int x = v;
#pragma unroll
    for (int off = 1; off < 64; off <<= 1) {
        int t = __shfl_up(x, off);
        if (lane >= off) x += t;
    }
    __shared__ int wsum[4];
    if (lane == 63) wsum[w] = x;
    __syncthreads();
    if (tid == 0) {
        int s = 0;
#pragma unroll
        for (int k = 0; k < 4; k++) { int t = wsum[k]; wsum[k] = s; s += t; }
    }
    __syncthreads();
    int incl = x + wsum[w];
    boff[tid] = incl - v;
    if (tid == 255) row_ptr[NNODES] = incl;  // total = NEDGES
}

__global__ void scan3(int* __restrict__ row_ptr, const int* __restrict__ boff,
                      int* __restrict__ cursor) {
    int i = blockIdx.x * 256 + threadIdx.x;
    if (i < NNODES) {
        int r = row_ptr[i] + boff[blockIdx.x];
        row_ptr[i] = r;
        cursor[i] = r;
    }
}

__global__ void fill_csr(const int* __restrict__ src, const int* __restrict__ dst,
                         int* __restrict__ cursor, int* __restrict__ col) {
    int e = blockIdx.x * 256 + threadIdx.x;
    if (e < NEDGES) {
        int d = dst[e];
        int pos = atomicAdd(&cursor[d], 1);
        col[pos] = src[e];
    }
}

// ---------------- row-block GEMM: C[M,128] = (A[M,K] @ B[K,128] + bias) * scale[row] ----------------
template <int K>
__global__ __launch_bounds__(256) void gemm128(const float* __restrict__ A,
                                               const float* __restrict__ B,
                                               const float* __restrict__ bias,
                                               const float* __restrict__ scale,
                                               float* __restrict__ C, int M) {
    __shared__ float as[16][K];
    int tid = threadIdx.x;
    int row0 = blockIdx.x * 16;
    for (int idx = tid; idx < 16 * K; idx += 256) {
        int r = idx / K, k = idx - r * K;
        int row = row0 + r;
        as[r][k] = (row < M) ? A[(size_t)row * K + k] : 0.0f;
    }
    __syncthreads();
    int d = tid & 127;       // output column
    int rg = tid >> 7;       // 0..1, row group
    float acc[8];
#pragma unroll
    for (int r = 0; r < 8; r++) acc[r] = 0.0f;
#pragma unroll 4
    for (int k = 0; k < K; k++) {
        float wv = B[k * 128 + d];
#pragma unroll
        for (int r = 0; r < 8; r++) acc[r] += as[rg * 8 + r][k] * wv;
    }
    float bv = bias ? bias[d] : 0.0f;
#pragma unroll
    for (int r = 0; r < 8; r++) {
        int row = row0 + rg * 8 + r;
        if (row < M) {
            float v = acc[r] + bv;
            if (scale) v *= scale[row];
            C[(size_t)row * 128 + d] = v;
        }
    }
}

// ---------------- CSR pull aggregate + bias (+ LN + ReLU) : one wave per dst row ----------------
__global__ __launch_bounds__(256) void aggregate(const float* __restrict__ hw,
                                                 const int* __restrict__ col,
                                                 const int* __restrict__ row_ptr,
                                                 const float* __restrict__ dinv,
                                                 const float* __restrict__ bias,
                                                 const float* __restrict__ g,
                                                 const float* __restrict__ b,
                                                 float* __restrict__ out, int do_ln) {
    int row = blockIdx.x * 4 + (threadIdx.x >> 6);
    int lane = threadIdx.x & 63;
    if (row >= NNODES) return;
    int e0 = row_ptr[row], e1 = row_ptr[row + 1];
    const size_t cb = (size_t)lane * 2;
    float2 acc = *(const float2*)&hw[(size_t)row * 128 + cb];  // self loop (hw pre-scaled by dinv[row])
    float2 acc1 = make_float2(0.f, 0.f), acc2 = make_float2(0.f, 0.f), acc3 = make_float2(0.f, 0.f);
    for (int base = e0; base < e1; base += 64) {
        int idx = base + lane;
        int myc = (idx < e1) ? col[idx] : 0;
        int cnt = min(64, e1 - base);
        int j = 0;
        for (; j + 4 <= cnt; j += 4) {
            int s0 = __shfl(myc, j), s1 = __shfl(myc, j + 1);
            int s2 = __shfl(myc, j + 2), s3 = __shfl(myc, j + 3);
            float2 v0 = *(const float2*)&hw[(size_t)s0 * 128 + cb];
            float2 v1 = *(const float2*)&hw[(size_t)s1 * 128 + cb];
            float2 v2 = *(const float2*)&hw[(size_t)s2 * 128 + cb];
            float2 v3 = *(const float2*)&hw[(size_t)s3 * 128 + cb];
            acc.x += v0.x; acc.y += v0.y;
            acc1.x += v1.x; acc1.y += v1.y;
            acc2.x += v2.x; acc2.y += v2.y;
            acc3.x += v3.x; acc3.y += v3.y;
        }
        for (; j < cnt; ++j) {
            int s = __shfl(myc, j);
            float2 v = *(const float2*)&hw[(size_t)s * 128 + cb];
            acc.x += v.x; acc.y += v.y;
        }
    }
    acc.x += acc1.x + acc2.x + acc3.x;
    acc.y += acc1.y + acc2.y + acc3.y;
    float sc = dinv[row];
    float2 bb = *(const float2*)&bias[cb];
    float hx = acc.x * sc + bb.x;
    float hy = acc.y * sc + bb.y;
    if (do_ln) {
        float sum = hx + hy;
#pragma unroll
        for (int off = 32; off >= 1; off >>= 1) sum += __shfl_xor(sum, off);
        float mu = sum * (1.0f / 128.0f);
        float dx = hx - mu, dy = hy - mu;
        float vs = dx * dx + dy * dy;
#pragma unroll
        for (int off = 32; off >= 1; off >>= 1) vs += __shfl_xor(vs, off);
        float rstd = rsqrtf(vs * (1.0f / 128.0f) + 1e-5f);
        float2 gg = *(const float2*)&g[cb];
        float2 lb = *(const float2*)&b[cb];
        hx = fmaxf(dx * rstd * gg.x + lb.x, 0.0f);
        hy = fmaxf(dy * rstd * gg.y + lb.y, 0.0f);
    }
    *(float2*)&out[(size_t)row * 128 + cb] = make_float2(hx, hy);
}

// ---------------- head: out[M,40] = h[M,128] @ W[128,40] + bias ----------------
__global__ __launch_bounds__(256) void head_gemm(const float* __restrict__ h,
                                                 const float* __restrict__ W,
                                                 const float* __restrict__ bias,
                                                 float* __restrict__ out, int M) {
    __shared__ float hs[32][128];
    int tid = threadIdx.x;
    int row0 = blockIdx.x * 32;
    for (int idx = tid; idx < 32 * 128; idx += 256) {
        int r = idx >> 7, k = idx & 127;
        int row = row0 + r;
        hs[r][k] = (row < M) ? h[(size_t)row * 128 + k] : 0.0f;
    }
    __syncthreads();
    int d = tid & 63;
    int rg = tid >> 6;  // 0..3 -> 8 rows each
    if (d < DOUTN) {
        float acc[8];
#pragma unroll
        for (int r = 0; r < 8; r++) acc[r] = 0.0f;
#pragma unroll 4
        for (int k = 0; k < 128; k++) {
            float wv = W[k * DOUTN + d];
#pragma unroll
            for (int r = 0; r < 8; r++) acc[r] += hs[rg * 8 + r][k] * wv;
        }
        float bv = bias[d];
#pragma unroll
        for (int r = 0; r < 8; r++) {
            int row = row0 + rg * 8 + r;
            if (row < M) out[(size_t)row * DOUTN + d] = acc[r] + bv;
        }
    }
}

extern "C" void kernel_launch(void* const* d_in, const int* in_sizes, int n_in,
                              void* d_out, int out_size, void* d_ws, size_t ws_size,
                              hipStream_t stream) {
    const float* x = (const float*)d_in[0];
    const int* ei = (const int*)d_in[1];
    const int* esrc = ei;
    const int* edst = ei + NEDGES;
    const float* W_enc = (const float*)d_in[2];
    const float* b_enc = (const float*)d_in[3];
    const float* W_pre = (const float*)d_in[4];
    const float* b_pre = (const float*)d_in[5];
    const float* Wc = (const float*)d_in[6];
    const float* bc = (const float*)d_in[7];
    const float* ln_g = (const float*)d_in[8];
    const float* ln_b = (const float*)d_in[9];
    const float* W_head = (const float*)d_in[10];
    const float* b_head = (const float*)d_in[11];
    float* out = (float*)d_out;

    char* ws = (char*)d_ws;
    const size_t nodeBytes = (size_t)NNODES * DMID * sizeof(float);  // 25.6 MB
    size_t off = 0;
    float* bufA = (float*)(ws + off); off += nodeBytes;
    float* bufB = (float*)(ws + off); off += nodeBytes;
    float* dinv = (float*)(ws + off); off += (size_t)NNODES * 4;
    int* counts = (int*)(ws + off); off += (size_t)NNODES * 4;
    int* cursor = (int*)(ws + off); off += (size_t)NNODES * 4;
    int* row_ptr = (int*)(ws + off); off += (size_t)(NNODES + 1) * 4 + 508; off &= ~(size_t)255;
    int* bsum = (int*)(ws + off); off += 256 * 4;
    int* boff = (int*)(ws + off); off += 256 * 4;
    int* col = (int*)(ws + off); off += (size_t)NEDGES * 4;

    // ---- CSR build + dinv ----
    zero_counts<<<NB1, 256, 0, stream>>>(counts);
    hist_dst<<<(NEDGES + 255) / 256, 256, 0, stream>>>(edst, counts);
    dinv_from_counts<<<NB1, 256, 0, stream>>>(counts, dinv);
    scan1<<<NB1, 256, 0, stream>>>(counts, row_ptr, bsum);
    scan2<<<1, 256, 0, stream>>>(bsum, boff, row_ptr);
    scan3<<<NB1, 256, 0, stream>>>(row_ptr, boff, cursor);
    fill_csr<<<(NEDGES + 255) / 256, 256, 0, stream>>>(esrc, edst, cursor, col);

    // ---- encoder + pre_mp ----
    gemm128<DINN><<<(NNODES + 15) / 16, 256, 0, stream>>>(x, W_enc, b_enc, nullptr, bufA, NNODES);
    gemm128<128><<<(NNODES + 15) / 16, 256, 0, stream>>>(bufA, W_pre, b_pre, nullptr, bufB, NNODES);

    // ---- 3 GCN layers: h in bufB, hw' in bufA ----
    for (int l = 0; l < 3; l++) {
        gemm128<128><<<(NNODES + 15) / 16, 256, 0, stream>>>(
            bufB, Wc + (size_t)l * 128 * 128, nullptr, dinv, bufA, NNODES);  // hw' = (h@Wc)*dinv
        aggregate<<<(NNODES + 3) / 4, 256, 0, stream>>>(
            bufA, col, row_ptr, dinv, bc + (size_t)l * 128,
            ln_g + (size_t)(l < 2 ? l : 0) * 128, ln_b + (size_t)(l < 2 ? l : 0) * 128,
            bufB, l < 2 ? 1 : 0);
    }

    // ---- head ----
    head_gemm<<<(NNODES + 31) / 32, 256, 0, stream>>>(bufB, W_head, b_head, out, NNODES);
}